// Round 2
// baseline (5230.355 us; speedup 1.0000x reference)
//
#include <hip/hip_runtime.h>
#include <hip/hip_bf16.h>
#include <math.h>

#define TOKENS 2048
#define DMODEL 768
#define NHEADS 12
#define NLAYERS 10

typedef __bf16 bf16x8 __attribute__((ext_vector_type(8)));
typedef float f32x4 __attribute__((ext_vector_type(4)));

__device__ __forceinline__ ushort f2bf(float f) {
  union { float f; unsigned u; } v; v.f = f;
  unsigned r = v.u + 0x7FFFu + ((v.u >> 16) & 1u);
  return (ushort)(r >> 16);
}

// ---------------- elementwise ----------------
__global__ __launch_bounds__(256) void temb_silu_kernel(const int* __restrict__ t,
    const float* __restrict__ freqs, ushort* __restrict__ st) {
  int idx = blockIdx.x * 256 + threadIdx.x;
  if (idx >= TOKENS * DMODEL) return;
  int row = idx / DMODEL, d = idx - row * DMODEL;
  float tv = (float)t[row];
  float v = (d < 384) ? sinf(tv * freqs[d]) : cosf(tv * freqs[d - 384]);
  float si = v / (1.f + expf(-v));
  st[idx] = f2bf(si);
}

__global__ __launch_bounds__(256) void cvt_bf16_kernel(const float* __restrict__ in,
    ushort* __restrict__ out, int n) {
  int idx = blockIdx.x * 256 + threadIdx.x;
  if (idx < n) out[idx] = f2bf(in[idx]);
}

__global__ __launch_bounds__(256) void emb_add_kernel(float* __restrict__ x,
    const int* __restrict__ token_ids, const float* __restrict__ h_emb,
    const float* __restrict__ w_emb) {
  int idx = blockIdx.x * 256 + threadIdx.x;
  if (idx >= TOKENS * DMODEL) return;
  int row = idx / DMODEL, d = idx - row * DMODEL;
  int p0 = token_ids[row * 3 + 1];
  int p1 = token_ids[row * 3 + 2];
  x[idx] += h_emb[p0 * DMODEL + d] + w_emb[p1 * DMODEL + d];
}

// ---------------- adaLN (layernorm * (1+scale) + shift) ----------------
template<bool BF16OUT>
__global__ __launch_bounds__(256) void adaln_kernel(const float* __restrict__ x,
    const float* __restrict__ c, const float* __restrict__ g, const float* __restrict__ be,
    ushort* __restrict__ hb, float* __restrict__ hf) {
  int row = blockIdx.x;
  int tid = threadIdx.x;
  const float* xr = x + (size_t)row * DMODEL;
  float v0 = xr[tid], v1 = xr[tid + 256], v2 = xr[tid + 512];
  float s = v0 + v1 + v2;
  float s2 = v0 * v0 + v1 * v1 + v2 * v2;
#pragma unroll
  for (int off = 32; off > 0; off >>= 1) {
    s += __shfl_xor(s, off);
    s2 += __shfl_xor(s2, off);
  }
  __shared__ float red[8];
  int wid = tid >> 6, lane = tid & 63;
  if (lane == 0) { red[wid] = s; red[wid + 4] = s2; }
  __syncthreads();
  s = red[0] + red[1] + red[2] + red[3];
  s2 = red[4] + red[5] + red[6] + red[7];
  float mu = s * (1.f / DMODEL);
  float var = s2 * (1.f / DMODEL) - mu * mu;
  float rs = rsqrtf(var + 1e-5f);
  const float* crow = c + (size_t)row * 1536;
#pragma unroll
  for (int i = 0; i < 3; ++i) {
    int d = tid + i * 256;
    float v = (i == 0) ? v0 : (i == 1 ? v1 : v2);
    float ln = (v - mu) * rs * g[d] + be[d];
    float hv = ln * (1.f + crow[d]) + crow[768 + d];
    if (BF16OUT) hb[(size_t)row * DMODEL + d] = f2bf(hv);
    else hf[(size_t)row * DMODEL + d] = hv;
  }
}

// ---------------- local attention: one wave per (b,s,h) ----------------
__global__ __launch_bounds__(256) void attn_kernel(const float* __restrict__ qkv,
    ushort* __restrict__ outb) {
  int wid = blockIdx.x * 4 + (threadIdx.x >> 6);
  int lane = threadIdx.x & 63;
  int h = wid % NHEADS;
  int row = wid / NHEADS;          // b*1024 + s
  int s_ = row & 1023;
  int b_ = row >> 10;
  int hq = s_ >> 5, wq = s_ & 31;
  float qd = qkv[(size_t)row * 2304 + h * 64 + lane];
  float sc[25];
  int jn[25];
#pragma unroll
  for (int dh = -2; dh <= 2; ++dh) {
#pragma unroll
    for (int dw = -2; dw <= 2; ++dw) {
      int idx = (dh + 2) * 5 + (dw + 2);
      int hn = hq + dh, wn = wq + dw;
      bool ok = ((unsigned)hn < 32u) && ((unsigned)wn < 32u);
      int j = (b_ << 10) + (hn << 5) + wn;
      jn[idx] = ok ? j : -1;
      float sv = -1e30f;
      if (ok) {
        float p = qd * qkv[(size_t)j * 2304 + 768 + h * 64 + lane];
#pragma unroll
        for (int off = 32; off > 0; off >>= 1) p += __shfl_xor(p, off);
        sv = p * 0.125f;
      }
      sc[idx] = sv;
    }
  }
  float m = -1e30f;
#pragma unroll
  for (int i = 0; i < 25; ++i) m = fmaxf(m, sc[i]);
  float l = 0.f;
#pragma unroll
  for (int i = 0; i < 25; ++i) {
    float p = (jn[i] >= 0) ? expf(sc[i] - m) : 0.f;
    sc[i] = p; l += p;
  }
  float inv = 1.f / l;
  float o = 0.f;
#pragma unroll
  for (int i = 0; i < 25; ++i) {
    if (jn[i] >= 0)
      o += sc[i] * qkv[(size_t)jn[i] * 2304 + 1536 + h * 64 + lane];
  }
  outb[(size_t)row * DMODEL + h * 64 + lane] = f2bf(o * inv);
}

// ---------------- GEMM: C[M,N] = A(bf16)[M,K] @ B(f32->bf16)[K,N] + bias ----------------
enum { EP_NONE = 0, EP_RESID = 1, EP_GELU = 2 };

template<int MODE>
__global__ __launch_bounds__(256) void gemm_kernel(const ushort* __restrict__ A,
    const float* __restrict__ Bw, const float* __restrict__ bias,
    float* __restrict__ Cf, ushort* __restrict__ Cb, int K, int N) {
  __shared__ ushort As[128][72];   // [m][k], pad->72 (144B rows, 16B aligned)
  __shared__ ushort Bs[128][72];   // [n][k] transposed
  int tid = threadIdx.x;
  int lane = tid & 63, wid = tid >> 6;
  int row0 = blockIdx.y * 128, col0 = blockIdx.x * 128;
  int wm = (wid >> 1) * 64, wn = (wid & 1) * 64;
  f32x4 acc[4][4];
#pragma unroll
  for (int i = 0; i < 4; ++i)
#pragma unroll
    for (int j = 0; j < 4; ++j)
      acc[i][j] = (f32x4){0.f, 0.f, 0.f, 0.f};

  int ar = tid >> 3;           // 0..31
  int akq = (tid & 7) * 8;     // 0..56
  int bkr = tid >> 5;          // 0..7
  int bnq = (tid & 31) * 4;    // 0..124

  for (int k0 = 0; k0 < K; k0 += 64) {
#pragma unroll
    for (int it = 0; it < 4; ++it) {
      int r = it * 32 + ar;
      const ushort* src = A + (size_t)(row0 + r) * K + k0 + akq;
      *reinterpret_cast<int4*>(&As[r][akq]) = *reinterpret_cast<const int4*>(src);
    }
#pragma unroll
    for (int it = 0; it < 8; ++it) {
      int kr = it * 8 + bkr;
      const float* src = Bw + (size_t)(k0 + kr) * N + col0 + bnq;
      float4 bv = *reinterpret_cast<const float4*>(src);
      Bs[bnq + 0][kr] = f2bf(bv.x);
      Bs[bnq + 1][kr] = f2bf(bv.y);
      Bs[bnq + 2][kr] = f2bf(bv.z);
      Bs[bnq + 3][kr] = f2bf(bv.w);
    }
    __syncthreads();
#pragma unroll
    for (int kk = 0; kk < 64; kk += 32) {
      bf16x8 a[4], b[4];
      int klo = kk + (lane >> 4) * 8;
#pragma unroll
      for (int mi = 0; mi < 4; ++mi)
        a[mi] = *reinterpret_cast<const bf16x8*>(&As[wm + mi * 16 + (lane & 15)][klo]);
#pragma unroll
      for (int ni = 0; ni < 4; ++ni)
        b[ni] = *reinterpret_cast<const bf16x8*>(&Bs[wn + ni * 16 + (lane & 15)][klo]);
#pragma unroll
      for (int mi = 0; mi < 4; ++mi)
#pragma unroll
        for (int ni = 0; ni < 4; ++ni)
          acc[mi][ni] = __builtin_amdgcn_mfma_f32_16x16x32_bf16(a[mi], b[ni], acc[mi][ni], 0, 0, 0);
    }
    __syncthreads();
  }
#pragma unroll
  for (int mi = 0; mi < 4; ++mi) {
#pragma unroll
    for (int ni = 0; ni < 4; ++ni) {
      int col = col0 + wn + ni * 16 + (lane & 15);
      float bv = bias[col];
#pragma unroll
      for (int r = 0; r < 4; ++r) {
        int row = row0 + wm + mi * 16 + (lane >> 4) * 4 + r;
        size_t off = (size_t)row * N + col;
        float v = acc[mi][ni][r] + bv;
        if (MODE == EP_RESID) { v += Cf[off]; Cf[off] = v; }
        else if (MODE == EP_GELU) { Cb[off] = f2bf(0.5f * v * (1.f + erff(v * 0.70710678118f))); }
        else { Cf[off] = v; }
      }
    }
  }
}

// ---------------- orchestration ----------------
extern "C" void kernel_launch(void* const* d_in, const int* in_sizes, int n_in,
                              void* d_out, int out_size, void* d_ws, size_t ws_size,
                              hipStream_t stream) {
  const float* x_in  = (const float*)d_in[0];
  const int*   t_in  = (const int*)d_in[1];
  const int*   tok   = (const int*)d_in[2];
  const float* Wp    = (const float*)d_in[3];
  const float* bp    = (const float*)d_in[4];
  const float* freqs = (const float*)d_in[5];
  const float* h_emb = (const float*)d_in[6];
  const float* w_emb = (const float*)d_in[7];
  const float* Wc1   = (const float*)d_in[8];
  const float* bc1   = (const float*)d_in[9];
  const float* g1    = (const float*)d_in[10];
  const float* be1   = (const float*)d_in[11];
  const float* Wqkv  = (const float*)d_in[12];
  const float* bqkv  = (const float*)d_in[13];
  const float* Wo    = (const float*)d_in[14];
  const float* bo    = (const float*)d_in[15];
  const float* Wc2   = (const float*)d_in[16];
  const float* bc2   = (const float*)d_in[17];
  const float* g2    = (const float*)d_in[18];
  const float* be2   = (const float*)d_in[19];
  const float* W1    = (const float*)d_in[20];
  const float* b1    = (const float*)d_in[21];
  const float* W2    = (const float*)d_in[22];
  const float* b2    = (const float*)d_in[23];
  const float* Wn    = (const float*)d_in[24];
  const float* bn    = (const float*)d_in[25];
  const float* gn    = (const float*)d_in[26];
  const float* bnn   = (const float*)d_in[27];

  char* w = (char*)d_ws;
  float*  x     = (float*)w;  w += (size_t)TOKENS * DMODEL * 4;
  ushort* st    = (ushort*)w; w += (size_t)TOKENS * DMODEL * 2;
  ushort* hb    = (ushort*)w; w += (size_t)TOKENS * DMODEL * 2;
  ushort* attnb = (ushort*)w; w += (size_t)TOKENS * DMODEL * 2;
  ushort* xinb  = (ushort*)w; w += (size_t)TOKENS * DMODEL * 2;
  float*  tmp   = (float*)w;  w += (size_t)TOKENS * 2304 * 4;   // shared: c(12MB)/qkv(18MB)/mid-bf16(12MB)
  ushort* midb  = (ushort*)tmp;

  const int n1 = TOKENS * DMODEL;
  dim3 blk(256);

  temb_silu_kernel<<<(n1 + 255) / 256, blk, 0, stream>>>(t_in, freqs, st);
  cvt_bf16_kernel<<<(n1 + 255) / 256, blk, 0, stream>>>(x_in, xinb, n1);
  gemm_kernel<EP_NONE><<<dim3(6, 16), blk, 0, stream>>>(xinb, Wp, bp, x, nullptr, 768, 768);
  emb_add_kernel<<<(n1 + 255) / 256, blk, 0, stream>>>(x, tok, h_emb, w_emb);

  for (int l = 0; l < NLAYERS; ++l) {
    gemm_kernel<EP_NONE><<<dim3(12, 16), blk, 0, stream>>>(
        st, Wc1 + (size_t)l * 768 * 1536, bc1 + (size_t)l * 1536, tmp, nullptr, 768, 1536);
    adaln_kernel<true><<<TOKENS, blk, 0, stream>>>(
        x, tmp, g1 + (size_t)l * 768, be1 + (size_t)l * 768, hb, nullptr);
    gemm_kernel<EP_NONE><<<dim3(18, 16), blk, 0, stream>>>(
        hb, Wqkv + (size_t)l * 768 * 2304, bqkv + (size_t)l * 2304, tmp, nullptr, 768, 2304);
    attn_kernel<<<TOKENS * NHEADS / 4, blk, 0, stream>>>(tmp, attnb);
    gemm_kernel<EP_RESID><<<dim3(6, 16), blk, 0, stream>>>(
        attnb, Wo + (size_t)l * 768 * 768, bo + (size_t)l * 768, x, nullptr, 768, 768);
    gemm_kernel<EP_NONE><<<dim3(12, 16), blk, 0, stream>>>(
        st, Wc2 + (size_t)l * 768 * 1536, bc2 + (size_t)l * 1536, tmp, nullptr, 768, 1536);
    adaln_kernel<true><<<TOKENS, blk, 0, stream>>>(
        x, tmp, g2 + (size_t)l * 768, be2 + (size_t)l * 768, hb, nullptr);
    gemm_kernel<EP_GELU><<<dim3(24, 16), blk, 0, stream>>>(
        hb, W1 + (size_t)l * 768 * 3072, b1 + (size_t)l * 3072, nullptr, midb, 768, 3072);
    gemm_kernel<EP_RESID><<<dim3(6, 16), blk, 0, stream>>>(
        midb, W2 + (size_t)l * 3072 * 768, b2 + (size_t)l * 768, x, nullptr, 3072, 768);
  }

  gemm_kernel<EP_NONE><<<dim3(12, 16), blk, 0, stream>>>(st, Wn, bn, tmp, nullptr, 768, 1536);
  adaln_kernel<false><<<TOKENS, blk, 0, stream>>>(x, tmp, gn, bnn, nullptr, (float*)d_out);
}

// Round 3
// 2951.360 us; speedup vs baseline: 1.7722x; 1.7722x over previous
//
#include <hip/hip_runtime.h>
#include <hip/hip_bf16.h>
#include <math.h>

#define TOKENS 2048
#define DMODEL 768
#define NHEADS 12
#define NLAYERS 10

typedef __bf16 bf16x8 __attribute__((ext_vector_type(8)));
typedef float f32x4 __attribute__((ext_vector_type(4)));

__device__ __forceinline__ ushort f2bf(float f) {
  union { float f; unsigned u; } v; v.f = f;
  unsigned r = v.u + 0x7FFFu + ((v.u >> 16) & 1u);
  return (ushort)(r >> 16);
}

// ---------------- transpose+convert: src f32 [K][N] -> dst bf16 [N][K] ----------------
__device__ __forceinline__ void tr_tile(const float* __restrict__ src, ushort* __restrict__ dst,
                                        int K, int N, int tk, int tn, int tid) {
  __shared__ ushort t[64][68];   // pad 68 -> 136B rows (8B aligned), ~2-4 way write conflicts only
  int k0 = tk * 64, n0 = tn * 64;
  int c4 = (tid & 15) * 4, rr = tid >> 4;   // rr 0..15
#pragma unroll
  for (int i = 0; i < 4; ++i) {
    int kk = rr + i * 16;
    float4 v = *reinterpret_cast<const float4*>(&src[(size_t)(k0 + kk) * N + n0 + c4]);
    t[c4 + 0][kk] = f2bf(v.x);
    t[c4 + 1][kk] = f2bf(v.y);
    t[c4 + 2][kk] = f2bf(v.z);
    t[c4 + 3][kk] = f2bf(v.w);
  }
  __syncthreads();
#pragma unroll
  for (int i = 0; i < 4; ++i) {
    int nn = rr + i * 16;
    ushort4 o;
    o.x = t[nn][c4 + 0]; o.y = t[nn][c4 + 1];
    o.z = t[nn][c4 + 2]; o.w = t[nn][c4 + 3];
    *reinterpret_cast<ushort4*>(&dst[(size_t)(n0 + nn) * K + k0 + c4]) = o;
  }
}

__global__ __launch_bounds__(256) void transpose_cvt_kernel(const float* __restrict__ src,
    ushort* __restrict__ dst, int K, int N) {
  tr_tile(src, dst, K, N, blockIdx.y, blockIdx.x, threadIdx.x);
}

// one dispatch per layer: all 6 weight mats (Wc1+Wc2 packed into wcT[3072][768])
__global__ __launch_bounds__(256) void transpose_layer_kernel(
    const float* __restrict__ wqkv, const float* __restrict__ wo,
    const float* __restrict__ wc1, const float* __restrict__ wc2,
    const float* __restrict__ w1, const float* __restrict__ w2,
    ushort* __restrict__ qkvT, ushort* __restrict__ woT, ushort* __restrict__ wcT,
    ushort* __restrict__ w1T, ushort* __restrict__ w2T) {
  int bx = blockIdx.x, tid = threadIdx.x;
  const float* src; ushort* dst; int K, N, t0;
  if (bx < 432)       { src = wqkv; dst = qkvT; K = 768;  N = 2304; t0 = bx; }
  else if (bx < 576)  { src = wo;   dst = woT;  K = 768;  N = 768;  t0 = bx - 432; }
  else if (bx < 864)  { src = wc1;  dst = wcT;  K = 768;  N = 1536; t0 = bx - 576; }
  else if (bx < 1152) { src = wc2;  dst = wcT + (size_t)1536 * 768; K = 768; N = 1536; t0 = bx - 864; }
  else if (bx < 1728) { src = w1;   dst = w1T;  K = 768;  N = 3072; t0 = bx - 1152; }
  else                { src = w2;   dst = w2T;  K = 3072; N = 768;  t0 = bx - 1728; }
  int ntn = N >> 6;
  tr_tile(src, dst, K, N, t0 / ntn, t0 % ntn, tid);
}

// ---------------- elementwise ----------------
__global__ __launch_bounds__(256) void temb_silu_kernel(const int* __restrict__ t,
    const float* __restrict__ freqs, ushort* __restrict__ st) {
  int idx = blockIdx.x * 256 + threadIdx.x;
  if (idx >= TOKENS * DMODEL) return;
  int row = idx / DMODEL, d = idx - row * DMODEL;
  float tv = (float)t[row];
  float v = (d < 384) ? sinf(tv * freqs[d]) : cosf(tv * freqs[d - 384]);
  float si = v / (1.f + expf(-v));
  st[idx] = f2bf(si);
}

__global__ __launch_bounds__(256) void cvt_bf16_kernel(const float* __restrict__ in,
    ushort* __restrict__ out, int n) {
  int idx = blockIdx.x * 256 + threadIdx.x;
  if (idx < n) out[idx] = f2bf(in[idx]);
}

__global__ __launch_bounds__(256) void emb_add_kernel(float* __restrict__ x,
    const int* __restrict__ token_ids, const float* __restrict__ h_emb,
    const float* __restrict__ w_emb) {
  int idx = blockIdx.x * 256 + threadIdx.x;
  if (idx >= TOKENS * DMODEL) return;
  int row = idx / DMODEL, d = idx - row * DMODEL;
  int p0 = token_ids[row * 3 + 1];
  int p1 = token_ids[row * 3 + 2];
  x[idx] += h_emb[p0 * DMODEL + d] + w_emb[p1 * DMODEL + d];
}

// ---------------- adaLN (layernorm * (1+scale) + shift) ----------------
template<bool BF16OUT>
__global__ __launch_bounds__(256) void adaln_kernel(const float* __restrict__ x,
    const float* __restrict__ c, int cstride, const float* __restrict__ g,
    const float* __restrict__ be, ushort* __restrict__ hb, float* __restrict__ hf) {
  int row = blockIdx.x;
  int tid = threadIdx.x;
  const float* xr = x + (size_t)row * DMODEL;
  float v0 = xr[tid], v1 = xr[tid + 256], v2 = xr[tid + 512];
  float s = v0 + v1 + v2;
  float s2 = v0 * v0 + v1 * v1 + v2 * v2;
#pragma unroll
  for (int off = 32; off > 0; off >>= 1) {
    s += __shfl_xor(s, off);
    s2 += __shfl_xor(s2, off);
  }
  __shared__ float red[8];
  int wid = tid >> 6, lane = tid & 63;
  if (lane == 0) { red[wid] = s; red[wid + 4] = s2; }
  __syncthreads();
  s = red[0] + red[1] + red[2] + red[3];
  s2 = red[4] + red[5] + red[6] + red[7];
  float mu = s * (1.f / DMODEL);
  float var = s2 * (1.f / DMODEL) - mu * mu;
  float rs = rsqrtf(var + 1e-5f);
  const float* crow = c + (size_t)row * cstride;
#pragma unroll
  for (int i = 0; i < 3; ++i) {
    int d = tid + i * 256;
    float v = (i == 0) ? v0 : (i == 1 ? v1 : v2);
    float ln = (v - mu) * rs * g[d] + be[d];
    float hv = ln * (1.f + crow[d]) + crow[768 + d];
    if (BF16OUT) hb[(size_t)row * DMODEL + d] = f2bf(hv);
    else hf[(size_t)row * DMODEL + d] = hv;
  }
}

// ---------------- local attention: one wave per (b,s,h) ----------------
__global__ __launch_bounds__(256) void attn_kernel(const float* __restrict__ qkv,
    ushort* __restrict__ outb) {
  int wid = blockIdx.x * 4 + (threadIdx.x >> 6);
  int lane = threadIdx.x & 63;
  int h = wid % NHEADS;
  int row = wid / NHEADS;          // b*1024 + s
  int s_ = row & 1023;
  int b_ = row >> 10;
  int hq = s_ >> 5, wq = s_ & 31;
  float qd = qkv[(size_t)row * 2304 + h * 64 + lane];
  float sc[25];
  int jn[25];
#pragma unroll
  for (int dh = -2; dh <= 2; ++dh) {
#pragma unroll
    for (int dw = -2; dw <= 2; ++dw) {
      int idx = (dh + 2) * 5 + (dw + 2);
      int hn = hq + dh, wn = wq + dw;
      bool ok = ((unsigned)hn < 32u) && ((unsigned)wn < 32u);
      int j = (b_ << 10) + (hn << 5) + wn;
      jn[idx] = ok ? j : -1;
      float sv = -1e30f;
      if (ok) {
        float p = qd * qkv[(size_t)j * 2304 + 768 + h * 64 + lane];
#pragma unroll
        for (int off = 32; off > 0; off >>= 1) p += __shfl_xor(p, off);
        sv = p * 0.125f;
      }
      sc[idx] = sv;
    }
  }
  float m = -1e30f;
#pragma unroll
  for (int i = 0; i < 25; ++i) m = fmaxf(m, sc[i]);
  float l = 0.f;
#pragma unroll
  for (int i = 0; i < 25; ++i) {
    float p = (jn[i] >= 0) ? expf(sc[i] - m) : 0.f;
    sc[i] = p; l += p;
  }
  float inv = 1.f / l;
  float o = 0.f;
#pragma unroll
  for (int i = 0; i < 25; ++i) {
    if (jn[i] >= 0)
      o += sc[i] * qkv[(size_t)jn[i] * 2304 + 1536 + h * 64 + lane];
  }
  outb[(size_t)row * DMODEL + h * 64 + lane] = f2bf(o * inv);
}

// ---------------- GEMM: C[M,N] = A(bf16 [M][K]) @ Bt(bf16 [N][K])^T + bias ----------------
enum { EP_NONE = 0, EP_RESID = 1, EP_GELU = 2 };

template<int BM, int BN, int MODE>
__global__ __launch_bounds__(256) void gemm_bb(const ushort* __restrict__ A,
    const ushort* __restrict__ Bt, const float* __restrict__ bias,
    const float* __restrict__ bias2, int bsplit,
    float* __restrict__ Cf, ushort* __restrict__ Cb, int K, int N) {
  constexpr int WM = BM / 2, WN = BN / 2;        // wave subtile (2x2 waves)
  constexpr int MI = WM / 16, NI = WN / 16;
  __shared__ ushort As[BM][72];                  // pad->72: 144B rows, 16B aligned
  __shared__ ushort Bs[BN][72];
  int tid = threadIdx.x, lane = tid & 63, wid = tid >> 6;
  int row0 = blockIdx.y * BM, col0 = blockIdx.x * BN;
  int wm = (wid >> 1) * WM, wn = (wid & 1) * WN;
  f32x4 acc[MI][NI];
#pragma unroll
  for (int i = 0; i < MI; ++i)
#pragma unroll
    for (int j = 0; j < NI; ++j)
      acc[i][j] = (f32x4){0.f, 0.f, 0.f, 0.f};

  int sr = tid >> 3;           // 0..31
  int sk = (tid & 7) * 8;      // 0..56

  for (int k0 = 0; k0 < K; k0 += 64) {
#pragma unroll
    for (int it = 0; it < BM / 32; ++it) {
      int r = it * 32 + sr;
      *reinterpret_cast<int4*>(&As[r][sk]) =
          *reinterpret_cast<const int4*>(&A[(size_t)(row0 + r) * K + k0 + sk]);
    }
#pragma unroll
    for (int it = 0; it < BN / 32; ++it) {
      int r = it * 32 + sr;
      *reinterpret_cast<int4*>(&Bs[r][sk]) =
          *reinterpret_cast<const int4*>(&Bt[(size_t)(col0 + r) * K + k0 + sk]);
    }
    __syncthreads();
#pragma unroll
    for (int kk = 0; kk < 64; kk += 32) {
      bf16x8 a[MI], b[NI];
      int klo = kk + (lane >> 4) * 8;
#pragma unroll
      for (int mi = 0; mi < MI; ++mi)
        a[mi] = *reinterpret_cast<const bf16x8*>(&As[wm + mi * 16 + (lane & 15)][klo]);
#pragma unroll
      for (int ni = 0; ni < NI; ++ni)
        b[ni] = *reinterpret_cast<const bf16x8*>(&Bs[wn + ni * 16 + (lane & 15)][klo]);
#pragma unroll
      for (int mi = 0; mi < MI; ++mi)
#pragma unroll
        for (int ni = 0; ni < NI; ++ni)
          acc[mi][ni] = __builtin_amdgcn_mfma_f32_16x16x32_bf16(a[mi], b[ni], acc[mi][ni], 0, 0, 0);
    }
    __syncthreads();
  }
#pragma unroll
  for (int mi = 0; mi < MI; ++mi) {
#pragma unroll
    for (int ni = 0; ni < NI; ++ni) {
      int col = col0 + wn + ni * 16 + (lane & 15);
      float bv = (col < bsplit) ? bias[col] : bias2[col - bsplit];
#pragma unroll
      for (int r = 0; r < 4; ++r) {
        int row = row0 + wm + mi * 16 + (lane >> 4) * 4 + r;
        size_t off = (size_t)row * N + col;
        float v = acc[mi][ni][r] + bv;
        if (MODE == EP_RESID) { v += Cf[off]; Cf[off] = v; }
        else if (MODE == EP_GELU) { Cb[off] = f2bf(0.5f * v * (1.f + erff(v * 0.70710678118f))); }
        else { Cf[off] = v; }
      }
    }
  }
}

// ---------------- orchestration ----------------
extern "C" void kernel_launch(void* const* d_in, const int* in_sizes, int n_in,
                              void* d_out, int out_size, void* d_ws, size_t ws_size,
                              hipStream_t stream) {
  const float* x_in  = (const float*)d_in[0];
  const int*   t_in  = (const int*)d_in[1];
  const int*   tok   = (const int*)d_in[2];
  const float* Wp    = (const float*)d_in[3];
  const float* bp    = (const float*)d_in[4];
  const float* freqs = (const float*)d_in[5];
  const float* h_emb = (const float*)d_in[6];
  const float* w_emb = (const float*)d_in[7];
  const float* Wc1   = (const float*)d_in[8];
  const float* bc1   = (const float*)d_in[9];
  const float* g1    = (const float*)d_in[10];
  const float* be1   = (const float*)d_in[11];
  const float* Wqkv  = (const float*)d_in[12];
  const float* bqkv  = (const float*)d_in[13];
  const float* Wo    = (const float*)d_in[14];
  const float* bo    = (const float*)d_in[15];
  const float* Wc2   = (const float*)d_in[16];
  const float* bc2   = (const float*)d_in[17];
  const float* g2    = (const float*)d_in[18];
  const float* be2   = (const float*)d_in[19];
  const float* W1    = (const float*)d_in[20];
  const float* b1    = (const float*)d_in[21];
  const float* W2    = (const float*)d_in[22];
  const float* b2    = (const float*)d_in[23];
  const float* Wn    = (const float*)d_in[24];
  const float* bn    = (const float*)d_in[25];
  const float* gn    = (const float*)d_in[26];
  const float* bnn   = (const float*)d_in[27];

  char* w = (char*)d_ws;
  auto alloc = [&](size_t bytes) { char* p = w; w += (bytes + 255) & ~(size_t)255; return p; };
  float*  x     = (float*)alloc((size_t)TOKENS * DMODEL * 4);
  ushort* st    = (ushort*)alloc((size_t)TOKENS * DMODEL * 2);
  ushort* hb    = (ushort*)alloc((size_t)TOKENS * DMODEL * 2);
  ushort* attnb = (ushort*)alloc((size_t)TOKENS * DMODEL * 2);
  ushort* xinb  = (ushort*)alloc((size_t)TOKENS * DMODEL * 2);
  float*  tmpc  = (float*)alloc((size_t)TOKENS * 3072 * 4);   // c1|c2 packed (and Wn out)
  float*  tmpq  = (float*)alloc((size_t)TOKENS * 2304 * 4);   // qkv
  ushort* midb  = (ushort*)alloc((size_t)TOKENS * 3072 * 2);  // gelu(ffn mid)
  ushort* wpT   = (ushort*)alloc((size_t)768 * 768 * 2);
  ushort* wnT   = (ushort*)alloc((size_t)1536 * 768 * 2);
  // per-layer transposed-weight arena (reused each layer)
  ushort* qkvT  = (ushort*)alloc((size_t)2304 * 768 * 2);
  ushort* woT   = (ushort*)alloc((size_t)768 * 768 * 2);
  ushort* wcT   = (ushort*)alloc((size_t)3072 * 768 * 2);
  ushort* w1T   = (ushort*)alloc((size_t)3072 * 768 * 2);
  ushort* w2T   = (ushort*)alloc((size_t)768 * 3072 * 2);

  const int n1 = TOKENS * DMODEL;
  dim3 blk(256);

  transpose_cvt_kernel<<<dim3(12, 12), blk, 0, stream>>>(Wp, wpT, 768, 768);
  transpose_cvt_kernel<<<dim3(24, 12), blk, 0, stream>>>(Wn, wnT, 768, 1536);
  temb_silu_kernel<<<(n1 + 255) / 256, blk, 0, stream>>>(t_in, freqs, st);
  cvt_bf16_kernel<<<(n1 + 255) / 256, blk, 0, stream>>>(x_in, xinb, n1);
  gemm_bb<64, 64, EP_NONE><<<dim3(12, 32), blk, 0, stream>>>(
      xinb, wpT, bp, bp, 768, x, nullptr, 768, 768);
  emb_add_kernel<<<(n1 + 255) / 256, blk, 0, stream>>>(x, tok, h_emb, w_emb);

  for (int l = 0; l < NLAYERS; ++l) {
    transpose_layer_kernel<<<2304, blk, 0, stream>>>(
        Wqkv + (size_t)l * 768 * 2304, Wo + (size_t)l * 768 * 768,
        Wc1 + (size_t)l * 768 * 1536, Wc2 + (size_t)l * 768 * 1536,
        W1 + (size_t)l * 768 * 3072, W2 + (size_t)l * 3072 * 768,
        qkvT, woT, wcT, w1T, w2T);
    // c = silu(temb) @ [Wc1|Wc2] + [bc1|bc2]   (N=3072)
    gemm_bb<128, 128, EP_NONE><<<dim3(24, 16), blk, 0, stream>>>(
        st, wcT, bc1 + (size_t)l * 1536, bc2 + (size_t)l * 1536, 1536, tmpc, nullptr, 768, 3072);
    adaln_kernel<true><<<TOKENS, blk, 0, stream>>>(
        x, tmpc, 3072, g1 + (size_t)l * 768, be1 + (size_t)l * 768, hb, nullptr);
    gemm_bb<128, 128, EP_NONE><<<dim3(18, 16), blk, 0, stream>>>(
        hb, qkvT, bqkv + (size_t)l * 2304, bqkv, 2304, tmpq, nullptr, 768, 2304);
    attn_kernel<<<TOKENS * NHEADS / 4, blk, 0, stream>>>(tmpq, attnb);
    gemm_bb<64, 64, EP_RESID><<<dim3(12, 32), blk, 0, stream>>>(
        attnb, woT, bo + (size_t)l * 768, bo, 768, x, nullptr, 768, 768);
    adaln_kernel<true><<<TOKENS, blk, 0, stream>>>(
        x, tmpc + 1536, 3072, g2 + (size_t)l * 768, be2 + (size_t)l * 768, hb, nullptr);
    gemm_bb<128, 128, EP_GELU><<<dim3(24, 16), blk, 0, stream>>>(
        hb, w1T, b1 + (size_t)l * 3072, b1, 3072, nullptr, midb, 768, 3072);
    gemm_bb<64, 64, EP_RESID><<<dim3(12, 32), blk, 0, stream>>>(
        midb, w2T, b2 + (size_t)l * 768, b2, 768, x, nullptr, 3072, 768);
  }

  gemm_bb<64, 64, EP_NONE><<<dim3(24, 32), blk, 0, stream>>>(
      st, wnT, bn, bn, 1536, tmpc, nullptr, 768, 1536);
  adaln_kernel<false><<<TOKENS, blk, 0, stream>>>(x, tmpc, 1536, gn, bnn, nullptr, (float*)d_out);
}

// Round 5
// 2317.848 us; speedup vs baseline: 2.2566x; 1.2733x over previous
//
#include <hip/hip_runtime.h>
#include <hip/hip_bf16.h>
#include <math.h>

#define TOKENS 2048
#define DMODEL 768
#define NHEADS 12
#define NLAYERS 10

typedef __bf16 bf16x8 __attribute__((ext_vector_type(8)));
typedef float f32x4 __attribute__((ext_vector_type(4)));

__device__ __forceinline__ ushort f2bf(float f) {
  union { float f; unsigned u; } v; v.f = f;
  unsigned r = v.u + 0x7FFFu + ((v.u >> 16) & 1u);
  return (ushort)(r >> 16);
}

// ---------------- transpose+convert: src f32 [K][N] -> dst bf16 [N][K] ----------------
__device__ __forceinline__ void tr_tile(const float* __restrict__ src, ushort* __restrict__ dst,
                                        int K, int N, int tk, int tn, int tid) {
  __shared__ ushort t[64][68];
  int k0 = tk * 64, n0 = tn * 64;
  int c4 = (tid & 15) * 4, rr = tid >> 4;
#pragma unroll
  for (int i = 0; i < 4; ++i) {
    int kk = rr + i * 16;
    float4 v = *reinterpret_cast<const float4*>(&src[(size_t)(k0 + kk) * N + n0 + c4]);
    t[c4 + 0][kk] = f2bf(v.x);
    t[c4 + 1][kk] = f2bf(v.y);
    t[c4 + 2][kk] = f2bf(v.z);
    t[c4 + 3][kk] = f2bf(v.w);
  }
  __syncthreads();
#pragma unroll
  for (int i = 0; i < 4; ++i) {
    int nn = rr + i * 16;
    ushort4 o;
    o.x = t[nn][c4 + 0]; o.y = t[nn][c4 + 1];
    o.z = t[nn][c4 + 2]; o.w = t[nn][c4 + 3];
    *reinterpret_cast<ushort4*>(&dst[(size_t)(n0 + nn) * K + k0 + c4]) = o;
  }
}

__global__ __launch_bounds__(256) void transpose_cvt_kernel(const float* __restrict__ src,
    ushort* __restrict__ dst, int K, int N) {
  tr_tile(src, dst, K, N, blockIdx.y, blockIdx.x, threadIdx.x);
}

__global__ __launch_bounds__(256) void transpose_layer_kernel(
    const float* __restrict__ wqkv, const float* __restrict__ wo,
    const float* __restrict__ wc1, const float* __restrict__ wc2,
    const float* __restrict__ w1, const float* __restrict__ w2,
    ushort* __restrict__ qkvT, ushort* __restrict__ woT, ushort* __restrict__ wcT,
    ushort* __restrict__ w1T, ushort* __restrict__ w2T) {
  int bx = blockIdx.x, tid = threadIdx.x;
  const float* src; ushort* dst; int K, N, t0;
  if (bx < 432)       { src = wqkv; dst = qkvT; K = 768;  N = 2304; t0 = bx; }
  else if (bx < 576)  { src = wo;   dst = woT;  K = 768;  N = 768;  t0 = bx - 432; }
  else if (bx < 864)  { src = wc1;  dst = wcT;  K = 768;  N = 1536; t0 = bx - 576; }
  else if (bx < 1152) { src = wc2;  dst = wcT + (size_t)1536 * 768; K = 768; N = 1536; t0 = bx - 864; }
  else if (bx < 1728) { src = w1;   dst = w1T;  K = 768;  N = 3072; t0 = bx - 1152; }
  else                { src = w2;   dst = w2T;  K = 3072; N = 768;  t0 = bx - 1728; }
  int ntn = N >> 6;
  tr_tile(src, dst, K, N, t0 / ntn, t0 % ntn, tid);
}

// ---------------- elementwise ----------------
__global__ __launch_bounds__(256) void temb_silu_kernel(const int* __restrict__ t,
    const float* __restrict__ freqs, ushort* __restrict__ st) {
  int idx = blockIdx.x * 256 + threadIdx.x;
  if (idx >= TOKENS * DMODEL) return;
  int row = idx / DMODEL, d = idx - row * DMODEL;
  float tv = (float)t[row];
  float v = (d < 384) ? sinf(tv * freqs[d]) : cosf(tv * freqs[d - 384]);
  float si = v / (1.f + expf(-v));
  st[idx] = f2bf(si);
}

__global__ __launch_bounds__(256) void cvt_bf16_kernel(const float* __restrict__ in,
    ushort* __restrict__ out, int n) {
  int idx = blockIdx.x * 256 + threadIdx.x;
  if (idx < n) out[idx] = f2bf(in[idx]);
}

__global__ __launch_bounds__(256) void emb_add_kernel(float* __restrict__ x,
    const int* __restrict__ token_ids, const float* __restrict__ h_emb,
    const float* __restrict__ w_emb) {
  int idx = blockIdx.x * 256 + threadIdx.x;
  if (idx >= TOKENS * DMODEL) return;
  int row = idx / DMODEL, d = idx - row * DMODEL;
  int p0 = token_ids[row * 3 + 1];
  int p1 = token_ids[row * 3 + 2];
  x[idx] += h_emb[p0 * DMODEL + d] + w_emb[p1 * DMODEL + d];
}

// ---------------- adaLN ----------------
template<bool BF16OUT>
__global__ __launch_bounds__(256) void adaln_kernel(const float* __restrict__ x,
    const float* __restrict__ c, int cstride, const float* __restrict__ g,
    const float* __restrict__ be, ushort* __restrict__ hb, float* __restrict__ hf) {
  int row = blockIdx.x;
  int tid = threadIdx.x;
  const float* xr = x + (size_t)row * DMODEL;
  float v0 = xr[tid], v1 = xr[tid + 256], v2 = xr[tid + 512];
  float s = v0 + v1 + v2;
  float s2 = v0 * v0 + v1 * v1 + v2 * v2;
#pragma unroll
  for (int off = 32; off > 0; off >>= 1) {
    s += __shfl_xor(s, off);
    s2 += __shfl_xor(s2, off);
  }
  __shared__ float red[8];
  int wid = tid >> 6, lane = tid & 63;
  if (lane == 0) { red[wid] = s; red[wid + 4] = s2; }
  __syncthreads();
  s = red[0] + red[1] + red[2] + red[3];
  s2 = red[4] + red[5] + red[6] + red[7];
  float mu = s * (1.f / DMODEL);
  float var = s2 * (1.f / DMODEL) - mu * mu;
  float rs = rsqrtf(var + 1e-5f);
  const float* crow = c + (size_t)row * cstride;
#pragma unroll
  for (int i = 0; i < 3; ++i) {
    int d = tid + i * 256;
    float v = (i == 0) ? v0 : (i == 1 ? v1 : v2);
    float ln = (v - mu) * rs * g[d] + be[d];
    float hv = ln * (1.f + crow[d]) + crow[768 + d];
    if (BF16OUT) hb[(size_t)row * DMODEL + d] = f2bf(hv);
    else hf[(size_t)row * DMODEL + d] = hv;
  }
}

// ---------------- MFMA neighborhood attention ----------------
// block = (h, r, b): Q tile = grid row r (32 tokens), K/V = rows r-2..r+2 (160 keys)
__global__ __launch_bounds__(256) void attn_mfma_kernel(const ushort* __restrict__ qkvb,
    ushort* __restrict__ outb) {
  __shared__ char smem[59904];
  ushort (*Qs)[72]  = (ushort(*)[72])(smem);            // 4608B
  ushort (*Ks)[72]  = (ushort(*)[72])(smem + 4608);     // 23040B (Vs, then Ks, then Ss overlay)
  float  (*Ss)[169] = (float (*)[169])(smem + 4608);    // 21632B (overlays Ks after QK)
  ushort (*VT)[168] = (ushort(*)[168])(smem + 27648);   // 21504B [d][key]
  ushort (*Ps)[168] = (ushort(*)[168])(smem + 49152);   // 10752B

  int h = blockIdx.x, r = blockIdx.y, b = blockIdx.z;
  int tid = threadIdx.x, lane = tid & 63, wid = tid >> 6;
  int tb = b * 1024 + r * 32;

  int w_ = tid >> 3, d0 = (tid & 7) * 8;
  // load Q tile + V rows (V goes into Ks region first)
  *reinterpret_cast<int4*>(&Qs[w_][d0]) =
      *reinterpret_cast<const int4*>(&qkvb[(size_t)(tb + w_) * 2304 + h * 64 + d0]);
#pragma unroll
  for (int i = 0; i < 5; ++i) {
    int rg = r - 2 + i;
    int rk = rg < 0 ? 0 : (rg > 31 ? 31 : rg);
    int tok = b * 1024 + rk * 32 + w_;
    *reinterpret_cast<int4*>(&Ks[i * 32 + w_][d0]) =
        *reinterpret_cast<const int4*>(&qkvb[(size_t)tok * 2304 + 1536 + h * 64 + d0]);
  }
  __syncthreads();
  // transpose V: Ks(row-major [key][d]) -> VT[d][key]
  {
    int d = tid & 63, kq = tid >> 6;   // wave kq owns keys kq*40..kq*40+39
#pragma unroll
    for (int s5 = 0; s5 < 5; ++s5) {
      int k0 = kq * 40 + s5 * 8;
      ushort tv[8];
#pragma unroll
      for (int j = 0; j < 8; ++j) tv[j] = Ks[k0 + j][d];
      int4 o;
      o.x = tv[0] | (tv[1] << 16); o.y = tv[2] | (tv[3] << 16);
      o.z = tv[4] | (tv[5] << 16); o.w = tv[6] | (tv[7] << 16);
      *reinterpret_cast<int4*>(&VT[d][k0]) = o;
    }
  }
  __syncthreads();
  // load K rows
#pragma unroll
  for (int i = 0; i < 5; ++i) {
    int rg = r - 2 + i;
    int rk = rg < 0 ? 0 : (rg > 31 ? 31 : rg);
    int tok = b * 1024 + rk * 32 + w_;
    *reinterpret_cast<int4*>(&Ks[i * 32 + w_][d0]) =
        *reinterpret_cast<const int4*>(&qkvb[(size_t)tok * 2304 + 768 + h * 64 + d0]);
  }
  __syncthreads();

  // QK^T: wave (mt = wid&1, n-tiles ntb..ntb+4)
  int mt = wid & 1, ntb = (wid >> 1) * 5;
  f32x4 acc[5];
#pragma unroll
  for (int i = 0; i < 5; ++i) acc[i] = (f32x4){0.f, 0.f, 0.f, 0.f};
#pragma unroll
  for (int ks = 0; ks < 2; ++ks) {
    int klo = ks * 32 + (lane >> 4) * 8;
    bf16x8 a = *reinterpret_cast<const bf16x8*>(&Qs[mt * 16 + (lane & 15)][klo]);
#pragma unroll
    for (int nt = 0; nt < 5; ++nt) {
      bf16x8 bv = *reinterpret_cast<const bf16x8*>(&Ks[(ntb + nt) * 16 + (lane & 15)][klo]);
      acc[nt] = __builtin_amdgcn_mfma_f32_16x16x32_bf16(a, bv, acc[nt], 0, 0, 0);
    }
  }
  __syncthreads();   // Ks dead; Ss overlays

  // masked, scaled scores -> Ss
#pragma unroll
  for (int nt = 0; nt < 5; ++nt) {
    int c = (ntb + nt) * 16 + (lane & 15);
    int i = c >> 5, wk = c & 31;
    int rg = r - 2 + i;
    bool rowok = (rg >= 0) && (rg < 32);
#pragma unroll
    for (int rr = 0; rr < 4; ++rr) {
      int q = mt * 16 + (lane >> 4) * 4 + rr;
      int dw = wk - q;
      bool ok = rowok && (dw <= 2) && (dw >= -2);
      Ss[q][c] = ok ? acc[nt][rr] * 0.125f : -1e9f;
    }
  }
  __syncthreads();

  // softmax: 8 threads per query row
  {
    int q = tid >> 3, seg = tid & 7;
    float pv[20];
    float m = -1e30f;
#pragma unroll
    for (int j = 0; j < 20; ++j) { pv[j] = Ss[q][seg * 20 + j]; m = fmaxf(m, pv[j]); }
    m = fmaxf(m, __shfl_xor(m, 1));
    m = fmaxf(m, __shfl_xor(m, 2));
    m = fmaxf(m, __shfl_xor(m, 4));
    float l = 0.f;
#pragma unroll
    for (int j = 0; j < 20; ++j) { float e = expf(pv[j] - m); pv[j] = e; l += e; }
    l += __shfl_xor(l, 1);
    l += __shfl_xor(l, 2);
    l += __shfl_xor(l, 4);
    float inv = 1.f / l;
#pragma unroll
    for (int j = 0; j < 20; ++j) Ps[q][seg * 20 + j] = f2bf(pv[j] * inv);
  }
  __syncthreads();

  // PV: wave (mt, n-tiles n0, n0+1), K-dim = 160
  int n0 = (wid >> 1) * 2;
  f32x4 oacc[2];
  oacc[0] = (f32x4){0.f, 0.f, 0.f, 0.f};
  oacc[1] = (f32x4){0.f, 0.f, 0.f, 0.f};
#pragma unroll
  for (int ks = 0; ks < 5; ++ks) {
    int klo = ks * 32 + (lane >> 4) * 8;
    bf16x8 a = *reinterpret_cast<const bf16x8*>(&Ps[mt * 16 + (lane & 15)][klo]);
#pragma unroll
    for (int ni = 0; ni < 2; ++ni) {
      bf16x8 bv = *reinterpret_cast<const bf16x8*>(&VT[(n0 + ni) * 16 + (lane & 15)][klo]);
      oacc[ni] = __builtin_amdgcn_mfma_f32_16x16x32_bf16(a, bv, oacc[ni], 0, 0, 0);
    }
  }
#pragma unroll
  for (int ni = 0; ni < 2; ++ni) {
    int d = (n0 + ni) * 16 + (lane & 15);
#pragma unroll
    for (int rr = 0; rr < 4; ++rr) {
      int q = mt * 16 + (lane >> 4) * 4 + rr;
      outb[(size_t)(tb + q) * 768 + h * 64 + d] = f2bf(oacc[ni][rr]);
    }
  }
}

// ---------------- GEMM: C[M,N] = A(bf16 [M][K]) @ Bt(bf16 [N][K])^T + bias ----------------
enum { EP_NONE = 0, EP_RESID = 1, EP_GELU = 2, EP_BF16 = 3 };

template<int BM, int BN, int MODE>
__global__ __launch_bounds__(256) void gemm_bb(const ushort* __restrict__ A,
    const ushort* __restrict__ Bt, const float* __restrict__ bias,
    const float* __restrict__ bias2, int bsplit,
    float* __restrict__ Cf, ushort* __restrict__ Cb, int K, int N) {
  constexpr int WM = BM / 2, WN = BN / 2;
  constexpr int MI = WM / 16, NI = WN / 16;
  __shared__ ushort As[BM][72];
  __shared__ ushort Bs[BN][72];
  int tid = threadIdx.x, lane = tid & 63, wid = tid >> 6;
  int row0 = blockIdx.y * BM, col0 = blockIdx.x * BN;
  int wm = (wid >> 1) * WM, wn = (wid & 1) * WN;
  f32x4 acc[MI][NI];
#pragma unroll
  for (int i = 0; i < MI; ++i)
#pragma unroll
    for (int j = 0; j < NI; ++j)
      acc[i][j] = (f32x4){0.f, 0.f, 0.f, 0.f};

  int sr = tid >> 3;
  int sk = (tid & 7) * 8;

  for (int k0 = 0; k0 < K; k0 += 64) {
#pragma unroll
    for (int it = 0; it < BM / 32; ++it) {
      int r = it * 32 + sr;
      *reinterpret_cast<int4*>(&As[r][sk]) =
          *reinterpret_cast<const int4*>(&A[(size_t)(row0 + r) * K + k0 + sk]);
    }
#pragma unroll
    for (int it = 0; it < BN / 32; ++it) {
      int r = it * 32 + sr;
      *reinterpret_cast<int4*>(&Bs[r][sk]) =
          *reinterpret_cast<const int4*>(&Bt[(size_t)(col0 + r) * K + k0 + sk]);
    }
    __syncthreads();
#pragma unroll
    for (int kk = 0; kk < 64; kk += 32) {
      bf16x8 a[MI], b[NI];
      int klo = kk + (lane >> 4) * 8;
#pragma unroll
      for (int mi = 0; mi < MI; ++mi)
        a[mi] = *reinterpret_cast<const bf16x8*>(&As[wm + mi * 16 + (lane & 15)][klo]);
#pragma unroll
      for (int ni = 0; ni < NI; ++ni)
        b[ni] = *reinterpret_cast<const bf16x8*>(&Bs[wn + ni * 16 + (lane & 15)][klo]);
#pragma unroll
      for (int mi = 0; mi < MI; ++mi)
#pragma unroll
        for (int ni = 0; ni < NI; ++ni)
          acc[mi][ni] = __builtin_amdgcn_mfma_f32_16x16x32_bf16(a[mi], b[ni], acc[mi][ni], 0, 0, 0);
    }
    __syncthreads();
  }
#pragma unroll
  for (int mi = 0; mi < MI; ++mi) {
#pragma unroll
    for (int ni = 0; ni < NI; ++ni) {
      int col = col0 + wn + ni * 16 + (lane & 15);
      float bv = (col < bsplit) ? bias[col] : bias2[col - bsplit];
#pragma unroll
      for (int r = 0; r < 4; ++r) {
        int row = row0 + wm + mi * 16 + (lane >> 4) * 4 + r;
        size_t off = (size_t)row * N + col;
        float v = acc[mi][ni][r] + bv;
        if (MODE == EP_RESID) { v += Cf[off]; Cf[off] = v; }
        else if (MODE == EP_GELU) { Cb[off] = f2bf(0.5f * v * (1.f + erff(v * 0.70710678118f))); }
        else if (MODE == EP_BF16) { Cb[off] = f2bf(v); }
        else { Cf[off] = v; }
      }
    }
  }
}

// ---------------- orchestration ----------------
extern "C" void kernel_launch(void* const* d_in, const int* in_sizes, int n_in,
                              void* d_out, int out_size, void* d_ws, size_t ws_size,
                              hipStream_t stream) {
  const float* x_in  = (const float*)d_in[0];
  const int*   t_in  = (const int*)d_in[1];
  const int*   tok   = (const int*)d_in[2];
  const float* Wp    = (const float*)d_in[3];
  const float* bp    = (const float*)d_in[4];
  const float* freqs = (const float*)d_in[5];
  const float* h_emb = (const float*)d_in[6];
  const float* w_emb = (const float*)d_in[7];
  const float* Wc1   = (const float*)d_in[8];
  const float* bc1   = (const float*)d_in[9];
  const float* g1    = (const float*)d_in[10];
  const float* be1   = (const float*)d_in[11];
  const float* Wqkv  = (const float*)d_in[12];
  const float* bqkv  = (const float*)d_in[13];
  const float* Wo    = (const float*)d_in[14];
  const float* bo    = (const float*)d_in[15];
  const float* Wc2   = (const float*)d_in[16];
  const float* bc2   = (const float*)d_in[17];
  const float* g2    = (const float*)d_in[18];
  const float* be2   = (const float*)d_in[19];
  const float* W1    = (const float*)d_in[20];
  const float* b1    = (const float*)d_in[21];
  const float* W2    = (const float*)d_in[22];
  const float* b2    = (const float*)d_in[23];
  const float* Wn    = (const float*)d_in[24];
  const float* bn    = (const float*)d_in[25];
  const float* gn    = (const float*)d_in[26];
  const float* bnn   = (const float*)d_in[27];

  char* w = (char*)d_ws;
  auto alloc = [&](size_t bytes) { char* p = w; w += (bytes + 255) & ~(size_t)255; return p; };
  float*  x     = (float*)alloc((size_t)TOKENS * DMODEL * 4);
  ushort* st    = (ushort*)alloc((size_t)TOKENS * DMODEL * 2);
  ushort* hb    = (ushort*)alloc((size_t)TOKENS * DMODEL * 2);
  ushort* attnb = (ushort*)alloc((size_t)TOKENS * DMODEL * 2);
  ushort* xinb  = (ushort*)alloc((size_t)TOKENS * DMODEL * 2);
  float*  tmpc  = (float*)alloc((size_t)TOKENS * 3072 * 4);   // c1|c2 packed (and Wn out)
  ushort* tmpqb = (ushort*)alloc((size_t)TOKENS * 2304 * 2);  // qkv (bf16)
  ushort* midb  = (ushort*)alloc((size_t)TOKENS * 3072 * 2);  // gelu(ffn mid)
  ushort* wpT   = (ushort*)alloc((size_t)768 * 768 * 2);
  ushort* wnT   = (ushort*)alloc((size_t)1536 * 768 * 2);
  ushort* qkvT  = (ushort*)alloc((size_t)2304 * 768 * 2);
  ushort* woT   = (ushort*)alloc((size_t)768 * 768 * 2);
  ushort* wcT   = (ushort*)alloc((size_t)3072 * 768 * 2);
  ushort* w1T   = (ushort*)alloc((size_t)3072 * 768 * 2);
  ushort* w2T   = (ushort*)alloc((size_t)768 * 3072 * 2);

  const int n1 = TOKENS * DMODEL;
  dim3 blk(256);

  transpose_cvt_kernel<<<dim3(12, 12), blk, 0, stream>>>(Wp, wpT, 768, 768);
  transpose_cvt_kernel<<<dim3(24, 12), blk, 0, stream>>>(Wn, wnT, 768, 1536);
  temb_silu_kernel<<<(n1 + 255) / 256, blk, 0, stream>>>(t_in, freqs, st);
  cvt_bf16_kernel<<<(n1 + 255) / 256, blk, 0, stream>>>(x_in, xinb, n1);
  gemm_bb<64, 64, EP_NONE><<<dim3(12, 32), blk, 0, stream>>>(
      xinb, wpT, bp, bp, 768, x, nullptr, 768, 768);
  emb_add_kernel<<<(n1 + 255) / 256, blk, 0, stream>>>(x, tok, h_emb, w_emb);

  for (int l = 0; l < NLAYERS; ++l) {
    transpose_layer_kernel<<<2304, blk, 0, stream>>>(
        Wqkv + (size_t)l * 768 * 2304, Wo + (size_t)l * 768 * 768,
        Wc1 + (size_t)l * 768 * 1536, Wc2 + (size_t)l * 768 * 1536,
        W1 + (size_t)l * 768 * 3072, W2 + (size_t)l * 3072 * 768,
        qkvT, woT, wcT, w1T, w2T);
    gemm_bb<128, 128, EP_NONE><<<dim3(24, 16), blk, 0, stream>>>(
        st, wcT, bc1 + (size_t)l * 1536, bc2 + (size_t)l * 1536, 1536, tmpc, nullptr, 768, 3072);
    adaln_kernel<true><<<TOKENS, blk, 0, stream>>>(
        x, tmpc, 3072, g1 + (size_t)l * 768, be1 + (size_t)l * 768, hb, nullptr);
    gemm_bb<128, 128, EP_BF16><<<dim3(18, 16), blk, 0, stream>>>(
        hb, qkvT, bqkv + (size_t)l * 2304, bqkv, 2304, nullptr, tmpqb, 768, 2304);
    attn_mfma_kernel<<<dim3(NHEADS, 32, 2), blk, 0, stream>>>(tmpqb, attnb);
    gemm_bb<64, 64, EP_RESID><<<dim3(12, 32), blk, 0, stream>>>(
        attnb, woT, bo + (size_t)l * 768, bo, 768, x, nullptr, 768, 768);
    adaln_kernel<true><<<TOKENS, blk, 0, stream>>>(
        x, tmpc + 1536, 3072, g2 + (size_t)l * 768, be2 + (size_t)l * 768, hb, nullptr);
    gemm_bb<128, 128, EP_GELU><<<dim3(24, 16), blk, 0, stream>>>(
        hb, w1T, b1 + (size_t)l * 3072, b1, 3072, nullptr, midb, 768, 3072);
    gemm_bb<64, 64, EP_RESID><<<dim3(12, 32), blk, 0, stream>>>(
        midb, w2T, b2 + (size_t)l * 768, b2, 768, x, nullptr, 3072, 768);
  }

  gemm_bb<64, 64, EP_NONE><<<dim3(24, 32), blk, 0, stream>>>(
      st, wnT, bn, bn, 1536, tmpc, nullptr, 768, 1536);
  adaln_kernel<false><<<TOKENS, blk, 0, stream>>>(x, tmpc, 1536, gn, bnn, nullptr, (float*)d_out);
}